// Round 8
// baseline (16.753 us; speedup 1.0000x reference)
//
#include <hip/hip_runtime.h>
#include <hip/hip_fp16.h>

#define B 4
#define CIN 64
#define OC 64
#define LMAX 144
#define HP 34
#define WP 34
#define HPW (HP*WP)            // 1156
#define NPIX 1024
#define RSTR 34                // row stride in half2 units (paired layout)
#define NPR 18                 // paired rows per channel: pr holds rows (pr, pr+16)
#define CSTR (NPR*RSTR)        // 612 half2 per channel
#define GUARD 4                // guard half2 slots at front
#define TOT_H2 (GUARD + CIN*CSTR)   // 39,172 half2 = 156,688 B
#define NCHUNK (TOT_H2/4)      // 9,793 16-byte chunks per batch image

typedef unsigned long long u64;
typedef __attribute__((address_space(1))) const unsigned glb_u32;
typedef __attribute__((address_space(3))) unsigned lds_u32;

static __device__ __forceinline__ unsigned pk(float lo, float hi) {
    return __builtin_bit_cast(unsigned, __builtin_amdgcn_cvt_pkrtz(lo, hi));
}

// Pre-kernel: format images into the paired-row f16 LDS layout in ws.
// ws[b*TOT_H2 + GUARD + c*612 + pr*34 + cc] = half2{padded(pr,cc+? ), ...}:
//   lo = padded row pr, hi = padded row pr+16, physical col cc = padded col-1
//   (cc 32,33 and out-of-range rows = 0). Guard slots zeroed.
// One block per (b,c); channel staged through LDS for coalescing.
__global__ __launch_bounds__(256) void format_kernel(
    const float* __restrict__ images, unsigned* __restrict__ ws) {
    __shared__ float ch[1024];
    const int bc = blockIdx.x;
    const int b = bc >> 6;
    const int c = bc & 63;
    const int t = threadIdx.x;
    const float* src = images + (size_t)bc * 1024;
    #pragma unroll
    for (int i = 0; i < 4; ++i) ch[i * 256 + t] = src[i * 256 + t];
    __syncthreads();
    unsigned* dst = ws + (size_t)b * TOT_H2 + GUARD + c * CSTR;
    for (int s = t; s < CSTR; s += 256) {
        int pr = s / RSTR;
        int cc = s - pr * RSTR;
        float lo = 0.f, hi = 0.f;
        int rlo = pr - 1;              // img row of padded row pr
        int rhi = pr + 15;             // img row of padded row pr+16
        if (cc < 32) {
            if ((unsigned)rlo < 32u) lo = ch[rlo * 32 + cc];
            if ((unsigned)rhi < 32u) hi = ch[rhi * 32 + cc];
        }
        dst[s] = pk(lo, hi);
    }
    if (c == 0 && t < GUARD) ws[(size_t)b * TOT_H2 + t] = 0u;
}

// Main kernel: one block per (b,o), 512 threads, 2 px/thread.
// Stage = pure global_load_lds DMA of the preformatted image (no VALU, no
// ds_write, no zeroing); tap decompose + bias overlap the DMA; gather is
// R7's 1-ds_read_b32-per-tap loop with taps via v_readlane.
__global__ __launch_bounds__(512, 1) void reconv_r8(
    const unsigned* __restrict__ wsimg,
    const int* __restrict__ tap_idx, const float* __restrict__ tap_w,
    const int* __restrict__ bias_index, const float* __restrict__ bias_value,
    float* __restrict__ out)
{
    __shared__ unsigned s_img[TOT_H2];

    const int bo = blockIdx.x;
    const int b = bo >> 6;
    const int o = bo & (OC - 1);
    const int t = threadIdx.x;
    const int lane = t & 63;
    const int wid = t >> 6;

    // --- Issue DMA first: 19 full rounds + 1 partial (65 chunks) ---
    const unsigned* src = wsimg + (size_t)b * TOT_H2;
    #pragma unroll
    for (int r = 0; r < 19; ++r) {
        int chunk = r * 512 + t;
        glb_u32* gp = (glb_u32*)(src + chunk * 4);
        lds_u32* lp = (lds_u32*)(s_img + (r * 512 + wid * 64) * 4);
        __builtin_amdgcn_global_load_lds(gp, lp, 16, 0, 0);
    }
    if (t < 65) {
        int chunk = 19 * 512 + t;
        glb_u32* gp = (glb_u32*)(src + chunk * 4);
        lds_u32* lp = (lds_u32*)(s_img + (19 * 512 + wid * 64) * 4);
        __builtin_amdgcn_global_load_lds(gp, lp, 16, 0, 0);
    }

    // --- Tap preload (overlaps DMA) ---
    const int* ti = tap_idx + o * LMAX;
    const float* tw = tap_w + o * LMAX;
    int vidx0 = ti[lane];
    int vidx1 = ti[64 + lane];
    int vidx2 = ti[128 + (lane & 15)];
    int vw0 = __float_as_int(tw[lane]);
    int vw1 = __float_as_int(tw[64 + lane]);
    int vw2 = __float_as_int(tw[128 + (lane & 15)]);

    // --- Bias: wave-parallel (OC == 64 == wave width) ---
    float bv = (bias_index[lane] == o) ? bias_value[lane] : 0.f;
    bv += __shfl_xor(bv, 32); bv += __shfl_xor(bv, 16); bv += __shfl_xor(bv, 8);
    bv += __shfl_xor(bv, 4);  bv += __shfl_xor(bv, 2);  bv += __shfl_xor(bv, 1);
    const float bias = bv;

    // --- Tap decompose: idx -> packed LDS byte offset (overlaps DMA) ---
    int voff0, voff1, voff2;
    {
        int c0 = vidx0 / HPW, r0 = vidx0 - c0 * HPW, kh0 = r0 / WP, kw0 = r0 - kh0 * WP;
        voff0 = (GUARD + c0 * CSTR + kh0 * RSTR + kw0 - 1) * 4;
        int c1 = vidx1 / HPW, r1 = vidx1 - c1 * HPW, kh1 = r1 / WP, kw1 = r1 - kh1 * WP;
        voff1 = (GUARD + c1 * CSTR + kh1 * RSTR + kw1 - 1) * 4;
        int c2 = vidx2 / HPW, r2 = vidx2 - c2 * HPW, kh2 = r2 / WP, kw2 = r2 - kh2 * WP;
        voff2 = (GUARD + c2 * CSTR + kh2 * RSTR + kw2 - 1) * 4;
    }

    __syncthreads();   // drains DMA (vmcnt) + all waves

    // --- Gather: 1 ds_read_b32 per tap ---
    const int w = t & 31;
    const int h0 = t >> 5;
    const int pxb = (h0 * RSTR + w) * 4;
    const char* sbase = (const char*)s_img;
    float a0 = 0.f, a1 = 0.f;
    #pragma unroll
    for (int j = 0; j < LMAX; ++j) {
        int vo, vw;
        if (j < 64)       { vo = __builtin_amdgcn_readlane(voff0, j);
                            vw = __builtin_amdgcn_readlane(vw0, j); }
        else if (j < 128) { vo = __builtin_amdgcn_readlane(voff1, j - 64);
                            vw = __builtin_amdgcn_readlane(vw1, j - 64); }
        else              { vo = __builtin_amdgcn_readlane(voff2, j - 128);
                            vw = __builtin_amdgcn_readlane(vw2, j - 128); }
        __half2 hv = *(const __half2*)(sbase + (vo + pxb));
        float wgt = __int_as_float(vw);
        a0 = fmaf(wgt, __low2float(hv), a0);
        a1 = fmaf(wgt, __high2float(hv), a1);
    }

    float* op = out + (size_t)bo * NPIX;
    op[h0 * 32 + w] = a0 + bias;
    op[(h0 + 16) * 32 + w] = a1 + bias;
}

extern "C" void kernel_launch(void* const* d_in, const int* in_sizes, int n_in,
                              void* d_out, int out_size, void* d_ws, size_t ws_size,
                              hipStream_t stream) {
    const float* images     = (const float*)d_in[0];
    const int*   tap_idx    = (const int*)d_in[1];
    const float* tap_w      = (const float*)d_in[2];
    const int*   bias_index = (const int*)d_in[3];
    const float* bias_value = (const float*)d_in[4];
    float* out = (float*)d_out;
    unsigned* wsimg = (unsigned*)d_ws;     // needs 4*156,688 B = 627 KB (ws >= 1.18 MB)

    format_kernel<<<B * CIN, 256, 0, stream>>>(images, wsimg);
    reconv_r8<<<B * OC, 512, 0, stream>>>(wsimg, tap_idx, tap_w,
                                          bias_index, bias_value, out);
}

// Round 9
// 12.981 us; speedup vs baseline: 1.2906x; 1.2906x over previous
//
#include <hip/hip_runtime.h>
#include <hip/hip_fp16.h>

#define B 4
#define CIN 64
#define OC 64
#define LMAX 144
#define HP 34
#define WP 34
#define HPW (HP*WP)            // 1156
#define NPIX 1024
#define RSTR 34                // row stride in half2 units (paired layout)
#define NPR 18                 // paired rows per channel: pr holds rows (pr, pr+16)
#define CSTR (NPR*RSTR)        // 612 half2 per channel
#define GUARD 4                // guard half2 slots at front
#define TOT_H2 (GUARD + CIN*CSTR)   // 39,172 half2 = 156,688 B

typedef unsigned long long u64;

static __device__ __forceinline__ unsigned pk(float lo, float hi) {
    return __builtin_bit_cast(unsigned, __builtin_amdgcn_cvt_pkrtz(lo, hi));
}

// One block per (b,o), 512 threads, 2 px/thread (rows h0, h0+16).
// Paired-row f16 layout: s_img[GUARD + c*612 + pr*34 + col] is a half2
// holding padded rows (pr, pr+16) at physical col = padded col - 1; the
// kw-1+w = -1 underflow lands in the previous slot's zeroed col (or guard).
// R9 vs R7: stage fully unrolled with explicit load-all-then-pack split
// (32 float4 in flight -> one L2 latency exposure instead of ~4), zeroing
// hoisted into the load shadow. Gather/bias/tap path identical to R7.
__global__ __launch_bounds__(512, 1) void reconv_r9(
    const float* __restrict__ images,
    const int* __restrict__ tap_idx, const float* __restrict__ tap_w,
    const int* __restrict__ bias_index, const float* __restrict__ bias_value,
    float* __restrict__ out)
{
    __shared__ unsigned s_img[TOT_H2];   // half2 per slot

    const int bo = blockIdx.x;
    const int b = bo >> 6;               // / OC
    const int o = bo & (OC - 1);
    const int t = threadIdx.x;
    const int lane = t & 63;

    // --- Issue ALL stage loads first (32 float4/thread, independent) ---
    const float4* img4 = (const float4*)images + (size_t)b * (CIN * 32 * 32 / 4);
    const int q = t & 7;                 // float4 index within a 32-col row
    const int g = t >> 3;                // 0..63
    float4 va[16], vd[16];
    #pragma unroll
    for (int i = 0; i < 16; ++i) {
        int rowid = i * 64 + g;          // 0..1023
        int c = rowid >> 4;
        int ir = rowid & 15;
        va[i] = img4[c * 256 + ir * 8 + q];
        vd[i] = img4[c * 256 + (ir + 16) * 8 + q];
    }

    // --- Tap preload (also in the load shadow) ---
    const int* ti = tap_idx + o * LMAX;
    const float* tw = tap_w + o * LMAX;
    int vidx0 = ti[lane];
    int vidx1 = ti[64 + lane];
    int vidx2 = ti[128 + (lane & 15)];
    int vw0 = __float_as_int(tw[lane]);
    int vw1 = __float_as_int(tw[64 + lane]);
    int vw2 = __float_as_int(tw[128 + (lane & 15)]);

    // --- Zero pads while loads are in flight ---
    u64* s64 = (u64*)s_img;
    if (t == 0) { s64[0] = 0ull; s64[1] = 0ull; }
    for (int i = t; i < CIN * NPR; i += 512) {
        int c = i / NPR;
        int pr = i - c * NPR;
        int e = GUARD + c * CSTR + pr * RSTR + 32;   // even -> 8B aligned
        *(u64*)&s_img[e] = 0ull;
    }

    // --- Bias: wave-parallel (OC == 64 == wave width) ---
    float bv = (bias_index[lane] == o) ? bias_value[lane] : 0.f;
    bv += __shfl_xor(bv, 32); bv += __shfl_xor(bv, 16); bv += __shfl_xor(bv, 8);
    bv += __shfl_xor(bv, 4);  bv += __shfl_xor(bv, 2);  bv += __shfl_xor(bv, 1);
    const float bias = bv;

    // --- Tap decompose: idx -> packed LDS byte offset ---
    int voff0, voff1, voff2;
    {
        int c0 = vidx0 / HPW, r0 = vidx0 - c0 * HPW, kh0 = r0 / WP, kw0 = r0 - kh0 * WP;
        voff0 = (GUARD + c0 * CSTR + kh0 * RSTR + kw0 - 1) * 4;
        int c1 = vidx1 / HPW, r1 = vidx1 - c1 * HPW, kh1 = r1 / WP, kw1 = r1 - kh1 * WP;
        voff1 = (GUARD + c1 * CSTR + kh1 * RSTR + kw1 - 1) * 4;
        int c2 = vidx2 / HPW, r2 = vidx2 - c2 * HPW, kh2 = r2 / WP, kw2 = r2 - kh2 * WP;
        voff2 = (GUARD + c2 * CSTR + kh2 * RSTR + kw2 - 1) * 4;
    }

    // --- Pack + ds_write phase ---
    #pragma unroll
    for (int i = 0; i < 16; ++i) {
        int rowid = i * 64 + g;
        int c = rowid >> 4;
        int ir = rowid & 15;
        unsigned u0 = pk(va[i].x, vd[i].x);
        unsigned u1 = pk(va[i].y, vd[i].y);
        unsigned u2 = pk(va[i].z, vd[i].z);
        unsigned u3 = pk(va[i].w, vd[i].w);
        int e = GUARD + c * CSTR + (ir + 1) * RSTR + 4 * q;   // even -> 8B aligned
        *(u64*)&s_img[e]     = ((u64)u1 << 32) | u0;
        *(u64*)&s_img[e + 2] = ((u64)u3 << 32) | u2;
    }
    // Specials: pr=0 = {pad0, img row 15}; pr=17 = {img row 16, pad33}.
    for (int i = t; i < CIN * 8 * 2; i += 512) {
        int c = i >> 4;
        int r2 = i & 15;
        int which = r2 >> 3;             // 0 -> pr=0, 1 -> pr=17
        int qq = r2 & 7;
        float4 v = img4[c * 256 + (which ? 16 : 15) * 8 + qq];
        unsigned u0 = which ? pk(v.x, 0.f) : pk(0.f, v.x);
        unsigned u1 = which ? pk(v.y, 0.f) : pk(0.f, v.y);
        unsigned u2 = which ? pk(v.z, 0.f) : pk(0.f, v.z);
        unsigned u3 = which ? pk(v.w, 0.f) : pk(0.f, v.w);
        int e = GUARD + c * CSTR + (which ? 17 : 0) * RSTR + 4 * qq;
        *(u64*)&s_img[e]     = ((u64)u1 << 32) | u0;
        *(u64*)&s_img[e + 2] = ((u64)u3 << 32) | u2;
    }

    __syncthreads();

    // --- Gather: 1 ds_read_b32 per tap; taps via v_readlane (no DS, no SMEM) ---
    const int w = t & 31;
    const int h0 = t >> 5;               // 0..15
    const int pxb = (h0 * RSTR + w) * 4; // thread's byte addend
    const char* sbase = (const char*)s_img;
    float a0 = 0.f, a1 = 0.f;
    #pragma unroll
    for (int j = 0; j < LMAX; ++j) {
        int vo, vw;
        if (j < 64)       { vo = __builtin_amdgcn_readlane(voff0, j);
                            vw = __builtin_amdgcn_readlane(vw0, j); }
        else if (j < 128) { vo = __builtin_amdgcn_readlane(voff1, j - 64);
                            vw = __builtin_amdgcn_readlane(vw1, j - 64); }
        else              { vo = __builtin_amdgcn_readlane(voff2, j - 128);
                            vw = __builtin_amdgcn_readlane(vw2, j - 128); }
        __half2 hv = *(const __half2*)(sbase + (vo + pxb));
        float wgt = __int_as_float(vw);
        a0 = fmaf(wgt, __low2float(hv), a0);
        a1 = fmaf(wgt, __high2float(hv), a1);
    }

    float* op = out + (size_t)bo * NPIX;
    op[h0 * 32 + w] = a0 + bias;
    op[(h0 + 16) * 32 + w] = a1 + bias;
}

extern "C" void kernel_launch(void* const* d_in, const int* in_sizes, int n_in,
                              void* d_out, int out_size, void* d_ws, size_t ws_size,
                              hipStream_t stream) {
    const float* images     = (const float*)d_in[0];
    const int*   tap_idx    = (const int*)d_in[1];
    const float* tap_w      = (const float*)d_in[2];
    const int*   bias_index = (const int*)d_in[3];
    const float* bias_value = (const float*)d_in[4];
    float* out = (float*)d_out;

    reconv_r9<<<B * OC, 512, 0, stream>>>(images, tap_idx, tap_w,
                                          bias_index, bias_value, out);
}

// Round 10
// 12.601 us; speedup vs baseline: 1.3295x; 1.0301x over previous
//
#include <hip/hip_runtime.h>
#include <hip/hip_fp16.h>

#define B 4
#define CIN 64
#define OC 64
#define LMAX 144
#define HP 34
#define WP 34
#define HPW (HP*WP)            // 1156
#define NPIX 1024
#define RSTR 34                // row stride in half2 units (paired layout)
#define NPR 18                 // paired rows per channel: pr holds rows (pr, pr+16)
#define CSTR (NPR*RSTR)        // 612 half2 per channel
#define GUARD 4                // guard half2 slots at front
#define TOT_H2 (GUARD + CIN*CSTR)   // 39,172 half2 = 156,688 B

typedef _Float16 h2_t __attribute__((ext_vector_type(2)));
typedef unsigned long long u64;

static __device__ __forceinline__ unsigned pk(float lo, float hi) {
    return __builtin_bit_cast(unsigned, __builtin_amdgcn_cvt_pkrtz(lo, hi));
}

// R10 = exact revert to R7 (best measured: 12.41 us).
// One block per (b,o), 512 threads, 2 px/thread (rows h0, h0+16).
// Paired-row f16 layout: s_img[GUARD + c*612 + pr*34 + col] is a half2
// holding padded rows (pr, pr+16) at physical col = padded col - 1; the
// kw-1+w = -1 underflow lands in the previous slot's zeroed col (or guard).
// Cost model (measured via R6/R8/R9 deltas): ~8 us graph-replay floor +
// ~4.3 us device (stage at L2-BW floor 1.8, gather ~1.3, pack/tail ~1).
__global__ __launch_bounds__(512, 1) void reconv_r7(
    const float* __restrict__ images,
    const int* __restrict__ tap_idx, const float* __restrict__ tap_w,
    const int* __restrict__ bias_index, const float* __restrict__ bias_value,
    float* __restrict__ out)
{
    __shared__ unsigned int s_img[TOT_H2];   // half2 per slot

    const int bo = blockIdx.x;
    const int b = bo >> 6;                   // / OC
    const int o = bo & (OC - 1);
    const int t = threadIdx.x;
    const int lane = t & 63;

    // --- Tap preload (issue these global loads first) ---
    const int* ti = tap_idx + o * LMAX;
    const float* tw = tap_w + o * LMAX;
    int vidx0 = ti[lane];
    int vidx1 = ti[64 + lane];
    int vidx2 = ti[128 + (lane & 15)];
    int vw0 = __float_as_int(tw[lane]);
    int vw1 = __float_as_int(tw[64 + lane]);
    int vw2 = __float_as_int(tw[128 + (lane & 15)]);

    // --- Bias: wave-parallel (OC == 64 == wave width) ---
    float bv = (bias_index[lane] == o) ? bias_value[lane] : 0.f;
    bv += __shfl_xor(bv, 32); bv += __shfl_xor(bv, 16); bv += __shfl_xor(bv, 8);
    bv += __shfl_xor(bv, 4);  bv += __shfl_xor(bv, 2);  bv += __shfl_xor(bv, 1);
    const float bias = bv;

    // --- Stage interior: image rows (ir, ir+16) packed as half2 via pkrtz ---
    const float4* img4 = (const float4*)images + (size_t)b * (CIN * 32 * 32 / 4);
    const int q = t & 7;                     // float4 index within a 32-col row
    const int g = t >> 3;                    // 0..63
    #pragma unroll 4
    for (int i = 0; i < 16; ++i) {
        int rowid = i * 64 + g;              // 0..1023
        int c = rowid >> 4;
        int ir = rowid & 15;
        float4 a = img4[c * 256 + ir * 8 + q];
        float4 d = img4[c * 256 + (ir + 16) * 8 + q];
        unsigned u0 = pk(a.x, d.x);
        unsigned u1 = pk(a.y, d.y);
        unsigned u2 = pk(a.z, d.z);
        unsigned u3 = pk(a.w, d.w);
        int e = GUARD + c * CSTR + (ir + 1) * RSTR + 4 * q;   // even -> 8B aligned
        *(u64*)&s_img[e]     = ((u64)u1 << 32) | u0;
        *(u64*)&s_img[e + 2] = ((u64)u3 << 32) | u2;
    }
    // Specials: pr=0 = {pad0, img row 15}; pr=17 = {img row 16, pad33}.
    for (int i = t; i < CIN * 8 * 2; i += 512) {
        int c = i >> 4;
        int r2 = i & 15;
        int which = r2 >> 3;                 // 0 -> pr=0, 1 -> pr=17
        int qq = r2 & 7;
        float4 v = img4[c * 256 + (which ? 16 : 15) * 8 + qq];
        unsigned u0 = which ? pk(v.x, 0.f) : pk(0.f, v.x);
        unsigned u1 = which ? pk(v.y, 0.f) : pk(0.f, v.y);
        unsigned u2 = which ? pk(v.z, 0.f) : pk(0.f, v.z);
        unsigned u3 = which ? pk(v.w, 0.f) : pk(0.f, v.w);
        int e = GUARD + c * CSTR + (which ? 17 : 0) * RSTR + 4 * qq;
        *(u64*)&s_img[e]     = ((u64)u1 << 32) | u0;
        *(u64*)&s_img[e + 2] = ((u64)u3 << 32) | u2;
    }

    // --- Tap decompose: idx -> packed LDS byte offset (per-lane VALU) ---
    int voff0, voff1, voff2;
    {
        int c0 = vidx0 / HPW, r0 = vidx0 - c0 * HPW, kh0 = r0 / WP, kw0 = r0 - kh0 * WP;
        voff0 = (GUARD + c0 * CSTR + kh0 * RSTR + kw0 - 1) * 4;
        int c1 = vidx1 / HPW, r1 = vidx1 - c1 * HPW, kh1 = r1 / WP, kw1 = r1 - kh1 * WP;
        voff1 = (GUARD + c1 * CSTR + kh1 * RSTR + kw1 - 1) * 4;
        int c2 = vidx2 / HPW, r2 = vidx2 - c2 * HPW, kh2 = r2 / WP, kw2 = r2 - kh2 * WP;
        voff2 = (GUARD + c2 * CSTR + kh2 * RSTR + kw2 - 1) * 4;
    }

    // --- Zero: guard + physical cols 32,33 of every (c,pr) (disjoint from interior) ---
    u64* s64 = (u64*)s_img;
    if (t == 0) { s64[0] = 0ull; s64[1] = 0ull; }
    for (int i = t; i < CIN * NPR; i += 512) {
        int c = i / NPR;
        int pr = i - c * NPR;
        int e = GUARD + c * CSTR + pr * RSTR + 32;      // even -> 8B aligned
        *(u64*)&s_img[e] = 0ull;
    }

    __syncthreads();

    // --- Gather: 1 ds_read_b32 per tap; taps via v_readlane (no DS, no SMEM) ---
    const int w = t & 31;
    const int h0 = t >> 5;                   // 0..15
    const int pxb = (h0 * RSTR + w) * 4;     // thread's byte addend
    const char* sbase = (const char*)s_img;
    float a0 = 0.f, a1 = 0.f;
    #pragma unroll
    for (int j = 0; j < LMAX; ++j) {
        int vo, vw;
        if (j < 64)       { vo = __builtin_amdgcn_readlane(voff0, j);
                            vw = __builtin_amdgcn_readlane(vw0, j); }
        else if (j < 128) { vo = __builtin_amdgcn_readlane(voff1, j - 64);
                            vw = __builtin_amdgcn_readlane(vw1, j - 64); }
        else              { vo = __builtin_amdgcn_readlane(voff2, j - 128);
                            vw = __builtin_amdgcn_readlane(vw2, j - 128); }
        __half2 hv = *(const __half2*)(sbase + (vo + pxb));
        float wgt = __int_as_float(vw);
        a0 = fmaf(wgt, __low2float(hv), a0);
        a1 = fmaf(wgt, __high2float(hv), a1);
    }

    float* op = out + (size_t)bo * NPIX;
    op[h0 * 32 + w] = a0 + bias;
    op[(h0 + 16) * 32 + w] = a1 + bias;
}

extern "C" void kernel_launch(void* const* d_in, const int* in_sizes, int n_in,
                              void* d_out, int out_size, void* d_ws, size_t ws_size,
                              hipStream_t stream) {
    const float* images     = (const float*)d_in[0];
    const int*   tap_idx    = (const int*)d_in[1];
    const float* tap_w      = (const float*)d_in[2];
    const int*   bias_index = (const int*)d_in[3];
    const float* bias_value = (const float*)d_in[4];
    float* out = (float*)d_out;

    reconv_r7<<<B * OC, 512, 0, stream>>>(images, tap_idx, tap_w,
                                          bias_index, bias_value, out);
}